// Round 3
// baseline (513.818 us; speedup 1.0000x reference)
//
#include <hip/hip_runtime.h>
#include <hip/hip_bf16.h>
#include <math.h>

// Problem constants
#define NN   4096
#define KK   24
#define IFZ  256
#define AH   12
#define AF   48
#define QP   4
#define VP   8

// nodeTab layout (floats per node, stride 2304):
//  [0,576)     q1 (roped in-place)
//  [576,1152)  k1 (roped in-place)
//  [1152,1728) v1
//  [1728,1872) q2 -> Tq2 (transformed in place)
//  [1872,2016) k2 (raw)
//  [2016,2304) v2 -> Tv2 (transformed in place)
#define TAB_STRIDE 2304
#define Q1OFF 0
#define K1OFF 576
#define V1OFF 1152
#define Q2OFF 1728
#define K2OFF 1872
#define V2OFF 2016

#define CAT_STRIDE 2496   // out1 576 | out2 1536 | oipa 288 | onorm 96
#define CAT_OUT2 576
#define CAT_OIPA 2112
#define CAT_ONRM 2400

#define WL      0.57735026918962576f   // sqrt(1/3)
#define C2      0.023570226039551584f  // 0.1*sqrt(2/(9*QP))
#define RSQRT48 0.14433756729740643f

// ---------------------------------------------------------------- pack W ----
__global__ __launch_bounds__(256) void pack_w(
    const float* __restrict__ Wq1, const float* __restrict__ Wk1,
    const float* __restrict__ Wv1, const float* __restrict__ Wq2,
    const float* __restrict__ Wk2, const float* __restrict__ Wv2,
    float* __restrict__ packW)
{
    int idx = blockIdx.x * 256 + threadIdx.x;   // < 256*2304
    int i = idx / TAB_STRIDE;
    int j = idx % TAB_STRIDE;
    float v;
    if (j < 576)       v = Wq1[i*576 + j];
    else if (j < 1152) v = Wk1[i*576 + (j-576)];
    else if (j < 1728) v = Wv1[i*576 + (j-1152)];
    else if (j < 1872) v = Wq2[i*144 + (j-1728)];
    else if (j < 2016) v = Wk2[i*144 + (j-1872)];
    else               v = Wv2[i*288 + (j-2016)];
    packW[idx] = v;
}

// -------------------------------------------------------------- GEMM 1 ------
// C[M x Nc] = A[M x Kc] * B[Kc x Nc], all row-major. BM=BN=64, BK=32.
__global__ __launch_bounds__(256) void gemm1(
    const float* __restrict__ A, const float* __restrict__ B,
    float* __restrict__ C, int M, int Nc, int Kc)
{
    __shared__ float sA[32][65];
    __shared__ float sB[32][65];
    int bx = blockIdx.x;   // col tile
    int by = blockIdx.y;   // row tile
    int tid = threadIdx.x;
    int tx = tid & 15, ty = tid >> 4;
    float acc[4][4] = {};
    for (int k0 = 0; k0 < Kc; k0 += 32) {
        #pragma unroll
        for (int l = 0; l < 2; ++l) {
            int idx = tid + l*256;
            int m = idx >> 3, k4 = (idx & 7) * 4;
            float4 av = *(const float4*)&A[(size_t)(by*64 + m)*Kc + k0 + k4];
            sA[k4+0][m] = av.x; sA[k4+1][m] = av.y;
            sA[k4+2][m] = av.z; sA[k4+3][m] = av.w;
        }
        #pragma unroll
        for (int l = 0; l < 2; ++l) {
            int idx = tid + l*256;
            int kk = idx >> 4, j = (idx & 15) * 4;
            float4 bv = *(const float4*)&B[(size_t)(k0 + kk)*Nc + bx*64 + j];
            sB[kk][j+0] = bv.x; sB[kk][j+1] = bv.y;
            sB[kk][j+2] = bv.z; sB[kk][j+3] = bv.w;
        }
        __syncthreads();
        #pragma unroll
        for (int kk = 0; kk < 32; ++kk) {
            float a[4], b[4];
            #pragma unroll
            for (int u = 0; u < 4; ++u) a[u] = sA[kk][ty*4+u];
            #pragma unroll
            for (int u = 0; u < 4; ++u) b[u] = sB[kk][tx*4+u];
            #pragma unroll
            for (int u = 0; u < 4; ++u)
                #pragma unroll
                for (int v = 0; v < 4; ++v) acc[u][v] += a[u]*b[v];
        }
        __syncthreads();
    }
    #pragma unroll
    for (int u = 0; u < 4; ++u)
        #pragma unroll
        for (int v = 0; v < 4; ++v)
            C[(size_t)(by*64 + ty*4+u)*Nc + bx*64 + tx*4+v] = acc[u][v];
}

// --------------------------------------------- GEMM 3 (+residual epilogue) --
__global__ __launch_bounds__(256) void gemm3(
    const float* __restrict__ A, const float* __restrict__ B,
    const float* __restrict__ x1, const float* __restrict__ bback,
    float* __restrict__ Hb, int M, int Nc, int Kc)
{
    __shared__ float sA[32][65];
    __shared__ float sB[32][65];
    int bx = blockIdx.x;
    int by = blockIdx.y;
    int tid = threadIdx.x;
    int tx = tid & 15, ty = tid >> 4;
    float acc[4][4] = {};
    for (int k0 = 0; k0 < Kc; k0 += 32) {
        #pragma unroll
        for (int l = 0; l < 2; ++l) {
            int idx = tid + l*256;
            int m = idx >> 3, k4 = (idx & 7) * 4;
            float4 av = *(const float4*)&A[(size_t)(by*64 + m)*Kc + k0 + k4];
            sA[k4+0][m] = av.x; sA[k4+1][m] = av.y;
            sA[k4+2][m] = av.z; sA[k4+3][m] = av.w;
        }
        #pragma unroll
        for (int l = 0; l < 2; ++l) {
            int idx = tid + l*256;
            int kk = idx >> 4, j = (idx & 15) * 4;
            float4 bv = *(const float4*)&B[(size_t)(k0 + kk)*Nc + bx*64 + j];
            sB[kk][j+0] = bv.x; sB[kk][j+1] = bv.y;
            sB[kk][j+2] = bv.z; sB[kk][j+3] = bv.w;
        }
        __syncthreads();
        #pragma unroll
        for (int kk = 0; kk < 32; ++kk) {
            float a[4], b[4];
            #pragma unroll
            for (int u = 0; u < 4; ++u) a[u] = sA[kk][ty*4+u];
            #pragma unroll
            for (int u = 0; u < 4; ++u) b[u] = sB[kk][tx*4+u];
            #pragma unroll
            for (int u = 0; u < 4; ++u)
                #pragma unroll
                for (int v = 0; v < 4; ++v) acc[u][v] += a[u]*b[v];
        }
        __syncthreads();
    }
    #pragma unroll
    for (int u = 0; u < 4; ++u)
        #pragma unroll
        for (int v = 0; v < 4; ++v) {
            int m = by*64 + ty*4+u;
            int c = bx*64 + tx*4+v;
            float h = 1.4142135623730951f * x1[(size_t)m*IFZ + c] + acc[u][v] + bback[c];
            Hb[(size_t)m*Nc + c] = h;
        }
}

// --------------------------------------------- per-node rope/affine epilogue
__global__ __launch_bounds__(256) void epilogue1(
    float* __restrict__ tab, const float* __restrict__ pos_emb,
    const float* __restrict__ affines)
{
    int node = blockIdx.x * 4 + (threadIdx.x >> 6);
    int lane = threadIdx.x & 63;
    float* row = tab + (size_t)node * TAB_STRIDE;
    const float* pe = pos_emb + node * (AF/2);

    // RoPE q1 (pairs 0..287) and k1 (288..575)
    for (int p = lane; p < 576; p += 64) {
        int part = p / 288;       // 0 -> q1, 1 -> k1
        int pp = p % 288;
        int a = pp / 24, t = pp % 24;
        float ang = pe[t];
        float c = cosf(ang), s = sinf(ang);
        float* b = row + part*576 + a*48 + 2*t;
        float xe = b[0], xo = b[1];
        b[0] = xe*c - xo*s;
        b[1] = xe*s + xo*c;
    }
    // affine
    float R[9], T[3];
    #pragma unroll
    for (int i = 0; i < 3; ++i) {
        #pragma unroll
        for (int j = 0; j < 3; ++j) R[i*3+j] = affines[node*12 + i*4 + j];
        T[i] = affines[node*12 + i*4 + 3];
    }
    // Tq2 (48 triples) then Tv2 (96 triples)
    for (int q = lane; q < 144; q += 64) {
        float* b = (q < 48) ? (row + Q2OFF + q*3) : (row + V2OFF + (q-48)*3);
        float x = b[0], y = b[1], z = b[2];
        b[0] = R[0]*x + R[1]*y + R[2]*z + T[0];
        b[1] = R[3]*x + R[4]*y + R[5]*z + T[1];
        b[2] = R[6]*x + R[7]*y + R[8]*z + T[2];
    }
}

// ------------------------------------------------------------ attention -----
// One block per node, 256 threads. Fully float4-vectorized gather.
// LDS paddings chosen for <=2-way bank aliasing on float4 reads:
//   sQ1 rows 48 -> 52 (a*52%32 in {0,20,8,28,...}: only a,a+8 collide)
//   sX2/sWbiaT rows -> 132 (k*132%32 = k*4%32: only k,k+8 collide)
__global__ __launch_bounds__(256) void attn_kernel(
    const float* __restrict__ tab, const float* __restrict__ x2,
    const float* __restrict__ affines, const float* __restrict__ Wbia,
    const float* __restrict__ gamma, const int* __restrict__ eidx,
    float* __restrict__ cat)
{
    int n = blockIdx.x;
    int tid = threadIdx.x;

    __shared__ float sQ1[12*52];
    __shared__ float sTq2[144];
    __shared__ float sX2[24*132];
    __shared__ float sWbiaT[12*132];
    __shared__ float sS[288];
    __shared__ float sOipa[288];
    __shared__ float sR[9], sT[3], sG[12];
    __shared__ int   sEoff[24];
    __shared__ float sMax[12], sInv[12];

    const float* row = tab + (size_t)n * TAB_STRIDE;

    // ---- staging (all float4) ----
    for (int j = tid; j < 144; j += 256) {            // q1: 144 f4
        int a = j / 12, r = j % 12;
        *(float4*)&sQ1[a*52 + r*4] = *(const float4*)&row[Q1OFF + j*4];
    }
    for (int j = tid; j < 36; j += 256)               // Tq2: 36 f4
        *(float4*)&sTq2[j*4] = *(const float4*)&row[Q2OFF + j*4];
    for (int j = tid; j < 768; j += 256) {            // x2: 24 x 32 f4
        int k = j >> 5, i4 = j & 31;
        *(float4*)&sX2[k*132 + i4*4] =
            *(const float4*)&x2[(size_t)n*(KK*128) + k*128 + i4*4];
    }
    for (int j = tid; j < 384; j += 256) {            // Wbia: load f4, transpose
        float4 v = *(const float4*)&Wbia[j*4];
        int base = j*4;
        float tmp[4] = {v.x, v.y, v.z, v.w};
        #pragma unroll
        for (int c = 0; c < 4; ++c) {
            int fl = base + c;                        // fl = i*12 + a
            int i = fl / 12, a = fl - i*12;
            sWbiaT[a*132 + i] = tmp[c];
        }
    }
    if (tid < 9)  sR[tid] = affines[n*12 + (tid/3)*4 + (tid%3)];
    if (tid < 3)  sT[tid] = affines[n*12 + tid*4 + 3];
    if (tid < 12) sG[tid] = gamma[tid];
    if (tid < 24) sEoff[tid] = eidx[n*KK + tid] * TAB_STRIDE;
    __syncthreads();

    // ---- scores: 288 (k,a) pairs, strided over 256 threads ----
    for (int j = tid; j < 288; j += 256) {
        int k = j / 12, a = j - k*12;
        const float* krow = tab + sEoff[k];
        // s1: q.k over 48 (12 f4)
        const float4* kq4 = (const float4*)(krow + K1OFF + a*48);
        const float4* qq4 = (const float4*)(sQ1 + a*52);
        float s1 = 0.f;
        #pragma unroll
        for (int i = 0; i < 12; ++i) {
            float4 kv = kq4[i], qv = qq4[i];
            s1 += kv.x*qv.x + kv.y*qv.y + kv.z*qv.z + kv.w*qv.w;
        }
        // bias: x2 . WbiaT over 128 (32 f4)
        const float4* xr4 = (const float4*)(sX2 + k*132);
        const float4* wr4 = (const float4*)(sWbiaT + a*132);
        float bias = 0.f;
        #pragma unroll 8
        for (int i = 0; i < 32; ++i) {
            float4 xv = xr4[i], wv = wr4[i];
            bias += xv.x*wv.x + xv.y*wv.y + xv.z*wv.z + xv.w*wv.w;
        }
        // s2: || Tq2 - T(k2) ||^2 over 4 points
        const float* k2 = krow + K2OFF + a*12;
        float4 k2a = *(const float4*)(k2);
        float4 k2b = *(const float4*)(k2+4);
        float4 k2c = *(const float4*)(k2+8);
        float kx[4] = {k2a.x, k2a.w, k2b.z, k2c.y};
        float ky[4] = {k2a.y, k2b.x, k2b.w, k2c.z};
        float kz[4] = {k2a.z, k2b.y, k2c.x, k2c.w};
        float ss = 0.f;
        #pragma unroll
        for (int p = 0; p < 4; ++p) {
            #pragma unroll
            for (int i = 0; i < 3; ++i) {
                float tk = sR[i*3]*kx[p] + sR[i*3+1]*ky[p] + sR[i*3+2]*kz[p] + sT[i];
                float d = sTq2[a*12 + p*3 + i] - tk;
                ss += d*d;
            }
        }
        sS[j] = WL*(s1*RSQRT48 + bias - C2*sG[a]*ss);
    }
    __syncthreads();
    // ---- softmax over k per head ----
    if (tid < 12) {
        float m = -1e30f;
        for (int k = 0; k < 24; ++k) m = fmaxf(m, sS[k*12 + tid]);
        float s = 0.f;
        for (int k = 0; k < 24; ++k) s += expf(sS[k*12 + tid] - m);
        sMax[tid] = m;
        sInv[tid] = 1.f / s;
    }
    __syncthreads();
    for (int j = tid; j < 288; j += 256) {
        int a = j % 12;
        sS[j] = expf(sS[j] - sMax[a]) * sInv[a];
    }
    __syncthreads();

    float* catRow = cat + (size_t)n * CAT_STRIDE;

    // ---- out1 (144 f4) + oipa (72 f4): 216 float4 items ----
    for (int j = tid; j < 216; j += 256) {
        if (j < 144) {
            int a = j / 12;
            float4 acc = {0.f, 0.f, 0.f, 0.f};
            #pragma unroll 6
            for (int k = 0; k < 24; ++k) {
                float w = sS[k*12 + a];
                float4 v = *(const float4*)&tab[sEoff[k] + V1OFF + j*4];
                acc.x += w*v.x; acc.y += w*v.y; acc.z += w*v.z; acc.w += w*v.w;
            }
            *(float4*)&catRow[j*4] = acc;
        } else {
            int j4 = j - 144;          // [0,72)
            int a = j4 / 6;
            float4 acc = {0.f, 0.f, 0.f, 0.f};
            #pragma unroll 6
            for (int k = 0; k < 24; ++k) {
                float w = sS[k*12 + a];
                float4 v = *(const float4*)&tab[sEoff[k] + V2OFF + j4*4];
                acc.x += w*v.x; acc.y += w*v.y; acc.z += w*v.z; acc.w += w*v.w;
            }
            *(float4*)&sOipa[j4*4] = acc;
        }
    }
    // ---- out2: 384 f4 ----
    for (int j = tid; j < 384; j += 256) {
        int a = j >> 5, i4 = j & 31;
        float4 acc = {0.f, 0.f, 0.f, 0.f};
        #pragma unroll 8
        for (int k = 0; k < 24; ++k) {
            float w = sS[k*12 + a];
            float4 v = *(const float4*)&sX2[k*132 + i4*4];
            acc.x += w*v.x; acc.y += w*v.y; acc.z += w*v.z; acc.w += w*v.w;
        }
        *(float4*)&catRow[CAT_OUT2 + j*4] = acc;
    }
    __syncthreads();
    // ---- inverse transform + norm: 96 points ----
    if (tid < 96) {
        int a = tid / 8, p = tid % 8;
        float o0 = sOipa[a*24 + p*3 + 0] - sT[0];
        float o1 = sOipa[a*24 + p*3 + 1] - sT[1];
        float o2 = sOipa[a*24 + p*3 + 2] - sT[2];
        float m0 = sR[0]*o0 + sR[3]*o1 + sR[6]*o2;
        float m1 = sR[1]*o0 + sR[4]*o1 + sR[7]*o2;
        float m2 = sR[2]*o0 + sR[5]*o1 + sR[8]*o2;
        catRow[CAT_OIPA + a*24 + p*3 + 0] = m0;
        catRow[CAT_OIPA + a*24 + p*3 + 1] = m1;
        catRow[CAT_OIPA + a*24 + p*3 + 2] = m2;
        catRow[CAT_ONRM + a*8 + p] = sqrtf(m0*m0 + m1*m1 + m2*m2);
    }
}

// ------------------------------------------------------------- layernorm ----
__global__ __launch_bounds__(256) void ln_kernel(
    const float* __restrict__ Hb, const float* __restrict__ g,
    const float* __restrict__ b, float* __restrict__ out)
{
    int n = blockIdx.x;
    int tid = threadIdx.x;
    float h = Hb[(size_t)n*IFZ + tid];
    float s = h, s2 = h*h;
    #pragma unroll
    for (int off = 32; off > 0; off >>= 1) {
        s  += __shfl_down(s,  off);
        s2 += __shfl_down(s2, off);
    }
    __shared__ float ws[4], ws2[4];
    int w = tid >> 6;
    if ((tid & 63) == 0) { ws[w] = s; ws2[w] = s2; }
    __syncthreads();
    float S  = ws[0] + ws[1] + ws[2] + ws[3];
    float S2 = ws2[0] + ws2[1] + ws2[2] + ws2[3];
    float mu = S * (1.f/IFZ);
    float var = S2 * (1.f/IFZ) - mu*mu;
    out[(size_t)n*IFZ + tid] = (h - mu) / sqrtf(var + 1e-5f) * g[tid] + b[tid];
}

// ---------------------------------------------------------------- launch ----
extern "C" void kernel_launch(void* const* d_in, const int* in_sizes, int n_in,
                              void* d_out, int out_size, void* d_ws, size_t ws_size,
                              hipStream_t stream)
{
    const float* x1      = (const float*)d_in[0];
    const float* x2      = (const float*)d_in[1];
    const float* affines = (const float*)d_in[2];
    const float* pos_emb = (const float*)d_in[3];
    const int*   eidx    = (const int*)  d_in[4];
    const float* Wq1     = (const float*)d_in[5];
    const float* Wk1     = (const float*)d_in[6];
    const float* Wv1     = (const float*)d_in[7];
    const float* Wq2     = (const float*)d_in[8];
    const float* Wk2     = (const float*)d_in[9];
    const float* Wv2     = (const float*)d_in[10];
    const float* Wbia    = (const float*)d_in[11];
    const float* gamma   = (const float*)d_in[12];
    const float* Wback   = (const float*)d_in[13];
    const float* bback   = (const float*)d_in[14];
    const float* ln_g    = (const float*)d_in[15];
    const float* ln_b    = (const float*)d_in[16];
    float* out = (float*)d_out;

    float* ws0 = (float*)d_ws;
    float* packW   = ws0;                                   // 256*2304
    float* nodeTab = packW + (size_t)IFZ*TAB_STRIDE;        // 4096*2304
    float* catBuf  = nodeTab + (size_t)NN*TAB_STRIDE;       // 4096*2496
    float* hbuf    = catBuf + (size_t)NN*CAT_STRIDE;        // 4096*256

    // 0) pack weights
    pack_w<<<(IFZ*TAB_STRIDE)/256, 256, 0, stream>>>(Wq1, Wk1, Wv1, Wq2, Wk2, Wv2, packW);
    // 1) projections: nodeTab = x1 @ packW
    gemm1<<<dim3(TAB_STRIDE/64, NN/64), 256, 0, stream>>>(x1, packW, nodeTab, NN, TAB_STRIDE, IFZ);
    // 1b) rope + affine transforms in place
    epilogue1<<<NN/4, 256, 0, stream>>>(nodeTab, pos_emb, affines);
    // 2) fused attention -> cat
    attn_kernel<<<NN, 256, 0, stream>>>(nodeTab, x2, affines, Wbia, gamma, eidx, catBuf);
    // 3) back-projection + residual -> hbuf
    gemm3<<<dim3(IFZ/64, NN/64), 256, 0, stream>>>(catBuf, Wback, x1, bback, hbuf, NN, IFZ, CAT_STRIDE);
    // 4) layernorm -> out
    ln_kernel<<<NN, 256, 0, stream>>>(hbuf, ln_g, ln_b, out);
}

// Round 4
// 411.044 us; speedup vs baseline: 1.2500x; 1.2500x over previous
//
#include <hip/hip_runtime.h>
#include <hip/hip_bf16.h>
#include <math.h>

// Problem constants
#define NN   4096
#define KK   24
#define IFZ  256
#define AH   12
#define AF   48
#define QP   4
#define VP   8

// nodeTab layout (floats per node, stride 2304):
//  [0,576)     q1 (roped in-place)
//  [576,1152)  k1 (roped in-place)
//  [1152,1728) v1
//  [1728,1872) q2 -> Tq2 (transformed in place)
//  [1872,2016) k2 (raw)
//  [2016,2304) v2 -> Tv2 (transformed in place)
#define TAB_STRIDE 2304
#define Q1OFF 0
#define K1OFF 576
#define V1OFF 1152
#define Q2OFF 1728
#define K2OFF 1872
#define V2OFF 2016

#define CAT_STRIDE 2496   // out1 576 | out2 1536 | oipa 288 | onorm 96
#define CAT_OUT2 576
#define CAT_OIPA 2112
#define CAT_ONRM 2400

#define SPLITK 6          // gemm3 split-K chunks: 6 x 416 (13 x 32) = 2496

#define WL      0.57735026918962576f   // sqrt(1/3)
#define C2      0.023570226039551584f  // 0.1*sqrt(2/(9*QP))
#define RSQRT48 0.14433756729740643f

// ---------------------------------------------------------------- pack W ----
__global__ __launch_bounds__(256) void pack_w(
    const float* __restrict__ Wq1, const float* __restrict__ Wk1,
    const float* __restrict__ Wv1, const float* __restrict__ Wq2,
    const float* __restrict__ Wk2, const float* __restrict__ Wv2,
    float* __restrict__ packW)
{
    int idx = blockIdx.x * 256 + threadIdx.x;   // < 256*2304
    int i = idx / TAB_STRIDE;
    int j = idx % TAB_STRIDE;
    float v;
    if (j < 576)       v = Wq1[i*576 + j];
    else if (j < 1152) v = Wk1[i*576 + (j-576)];
    else if (j < 1728) v = Wv1[i*576 + (j-1152)];
    else if (j < 1872) v = Wq2[i*144 + (j-1728)];
    else if (j < 2016) v = Wk2[i*144 + (j-1872)];
    else               v = Wv2[i*288 + (j-2016)];
    packW[idx] = v;
}

// -------------------------------------------------------------- GEMM 1 ------
// C[M x Nc] = A[M x Kc] * B[Kc x Nc], row-major. BM=BN=64, BK=32.
// LDS rows padded to 68 floats (16B-aligned); inner loop = 2x ds_read_b128
// + 16 FMA per k-step (FMA-issue-bound, not LDS-pipe-bound).
__global__ __launch_bounds__(256) void gemm1(
    const float* __restrict__ A, const float* __restrict__ B,
    float* __restrict__ C, int M, int Nc, int Kc)
{
    __shared__ __align__(16) float sA[32][68];
    __shared__ __align__(16) float sB[32][68];
    int bx = blockIdx.x;   // col tile
    int by = blockIdx.y;   // row tile
    int tid = threadIdx.x;
    int tx = tid & 15, ty = tid >> 4;
    float acc[4][4] = {};
    for (int k0 = 0; k0 < Kc; k0 += 32) {
        // A tile: 64 rows x 32 k, float4 loads, transposed scalar stores
        #pragma unroll
        for (int l = 0; l < 2; ++l) {
            int idx = tid + l*256;
            int m = idx >> 3, k4 = (idx & 7) * 4;
            float4 av = *(const float4*)&A[(size_t)(by*64 + m)*Kc + k0 + k4];
            sA[k4+0][m] = av.x; sA[k4+1][m] = av.y;
            sA[k4+2][m] = av.z; sA[k4+3][m] = av.w;
        }
        // B tile: 32 k x 64 cols, direct float4 stores (16 lanes/row: conflict-free)
        #pragma unroll
        for (int l = 0; l < 2; ++l) {
            int idx = tid + l*256;
            int kk = idx >> 4, j = (idx & 15) * 4;
            *(float4*)&sB[kk][j] = *(const float4*)&B[(size_t)(k0 + kk)*Nc + bx*64 + j];
        }
        __syncthreads();
        #pragma unroll
        for (int kk = 0; kk < 32; ++kk) {
            float4 a4 = *(const float4*)&sA[kk][ty*4];
            float4 b4 = *(const float4*)&sB[kk][tx*4];
            float a[4] = {a4.x, a4.y, a4.z, a4.w};
            float b[4] = {b4.x, b4.y, b4.z, b4.w};
            #pragma unroll
            for (int u = 0; u < 4; ++u)
                #pragma unroll
                for (int v = 0; v < 4; ++v) acc[u][v] += a[u]*b[v];
        }
        __syncthreads();
    }
    #pragma unroll
    for (int u = 0; u < 4; ++u) {
        float4 o = {acc[u][0], acc[u][1], acc[u][2], acc[u][3]};
        *(float4*)&C[(size_t)(by*64 + ty*4+u)*Nc + bx*64 + tx*4] = o;
    }
}

// --------------------------------------- GEMM 3, split-K (writes partials) --
// A = catBuf [NN x 2496], B = Wback [2496 x 256]. Grid (4, 64, SPLITK).
// Chunk s covers k in [s*416, (s+1)*416) = 13 k-tiles of 32.
__global__ __launch_bounds__(256) void gemm3s(
    const float* __restrict__ A, const float* __restrict__ B,
    float* __restrict__ P)
{
    __shared__ __align__(16) float sA[32][68];
    __shared__ __align__(16) float sB[32][68];
    int bx = blockIdx.x;
    int by = blockIdx.y;
    int s  = blockIdx.z;
    int tid = threadIdx.x;
    int tx = tid & 15, ty = tid >> 4;
    const int Kc = CAT_STRIDE, Nc = IFZ;
    float* Pp = P + (size_t)s * NN * IFZ;
    float acc[4][4] = {};
    for (int ki = 0; ki < 13; ++ki) {
        int k0 = s*416 + ki*32;
        #pragma unroll
        for (int l = 0; l < 2; ++l) {
            int idx = tid + l*256;
            int m = idx >> 3, k4 = (idx & 7) * 4;
            float4 av = *(const float4*)&A[(size_t)(by*64 + m)*Kc + k0 + k4];
            sA[k4+0][m] = av.x; sA[k4+1][m] = av.y;
            sA[k4+2][m] = av.z; sA[k4+3][m] = av.w;
        }
        #pragma unroll
        for (int l = 0; l < 2; ++l) {
            int idx = tid + l*256;
            int kk = idx >> 4, j = (idx & 15) * 4;
            *(float4*)&sB[kk][j] = *(const float4*)&B[(size_t)(k0 + kk)*Nc + bx*64 + j];
        }
        __syncthreads();
        #pragma unroll
        for (int kk = 0; kk < 32; ++kk) {
            float4 a4 = *(const float4*)&sA[kk][ty*4];
            float4 b4 = *(const float4*)&sB[kk][tx*4];
            float a[4] = {a4.x, a4.y, a4.z, a4.w};
            float b[4] = {b4.x, b4.y, b4.z, b4.w};
            #pragma unroll
            for (int u = 0; u < 4; ++u)
                #pragma unroll
                for (int v = 0; v < 4; ++v) acc[u][v] += a[u]*b[v];
        }
        __syncthreads();
    }
    #pragma unroll
    for (int u = 0; u < 4; ++u) {
        float4 o = {acc[u][0], acc[u][1], acc[u][2], acc[u][3]};
        *(float4*)&Pp[(size_t)(by*64 + ty*4+u)*Nc + bx*64 + tx*4] = o;
    }
}

// --------------------------------------------- per-node rope/affine epilogue
__global__ __launch_bounds__(256) void epilogue1(
    float* __restrict__ tab, const float* __restrict__ pos_emb,
    const float* __restrict__ affines)
{
    int node = blockIdx.x * 4 + (threadIdx.x >> 6);
    int lane = threadIdx.x & 63;
    float* row = tab + (size_t)node * TAB_STRIDE;
    const float* pe = pos_emb + node * (AF/2);

    // RoPE q1 (pairs 0..287) and k1 (288..575)
    for (int p = lane; p < 576; p += 64) {
        int part = p / 288;       // 0 -> q1, 1 -> k1
        int pp = p % 288;
        int a = pp / 24, t = pp % 24;
        float ang = pe[t];
        float c = cosf(ang), s = sinf(ang);
        float* b = row + part*576 + a*48 + 2*t;
        float xe = b[0], xo = b[1];
        b[0] = xe*c - xo*s;
        b[1] = xe*s + xo*c;
    }
    // affine
    float R[9], T[3];
    #pragma unroll
    for (int i = 0; i < 3; ++i) {
        #pragma unroll
        for (int j = 0; j < 3; ++j) R[i*3+j] = affines[node*12 + i*4 + j];
        T[i] = affines[node*12 + i*4 + 3];
    }
    // Tq2 (48 triples) then Tv2 (96 triples)
    for (int q = lane; q < 144; q += 64) {
        float* b = (q < 48) ? (row + Q2OFF + q*3) : (row + V2OFF + (q-48)*3);
        float x = b[0], y = b[1], z = b[2];
        b[0] = R[0]*x + R[1]*y + R[2]*z + T[0];
        b[1] = R[3]*x + R[4]*y + R[5]*z + T[1];
        b[2] = R[6]*x + R[7]*y + R[8]*z + T[2];
    }
}

// ------------------------------------------------------------ attention -----
// One block per node, 256 threads. Fully float4-vectorized gather.
__global__ __launch_bounds__(256) void attn_kernel(
    const float* __restrict__ tab, const float* __restrict__ x2,
    const float* __restrict__ affines, const float* __restrict__ Wbia,
    const float* __restrict__ gamma, const int* __restrict__ eidx,
    float* __restrict__ cat)
{
    int n = blockIdx.x;
    int tid = threadIdx.x;

    __shared__ __align__(16) float sQ1[12*52];
    __shared__ __align__(16) float sTq2[144];
    __shared__ __align__(16) float sX2[24*132];
    __shared__ __align__(16) float sWbiaT[12*132];
    __shared__ float sS[288];
    __shared__ float sOipa[288];
    __shared__ float sR[9], sT[3], sG[12];
    __shared__ int   sEoff[24];
    __shared__ float sMax[12], sInv[12];

    const float* row = tab + (size_t)n * TAB_STRIDE;

    // ---- staging (all float4) ----
    for (int j = tid; j < 144; j += 256) {            // q1: 144 f4
        int a = j / 12, r = j % 12;
        *(float4*)&sQ1[a*52 + r*4] = *(const float4*)&row[Q1OFF + j*4];
    }
    for (int j = tid; j < 36; j += 256)               // Tq2: 36 f4
        *(float4*)&sTq2[j*4] = *(const float4*)&row[Q2OFF + j*4];
    for (int j = tid; j < 768; j += 256) {            // x2: 24 x 32 f4
        int k = j >> 5, i4 = j & 31;
        *(float4*)&sX2[k*132 + i4*4] =
            *(const float4*)&x2[(size_t)n*(KK*128) + k*128 + i4*4];
    }
    for (int j = tid; j < 384; j += 256) {            // Wbia: load f4, transpose
        float4 v = *(const float4*)&Wbia[j*4];
        int base = j*4;
        float tmp[4] = {v.x, v.y, v.z, v.w};
        #pragma unroll
        for (int c = 0; c < 4; ++c) {
            int fl = base + c;                        // fl = i*12 + a
            int i = fl / 12, a = fl - i*12;
            sWbiaT[a*132 + i] = tmp[c];
        }
    }
    if (tid < 9)  sR[tid] = affines[n*12 + (tid/3)*4 + (tid%3)];
    if (tid < 3)  sT[tid] = affines[n*12 + tid*4 + 3];
    if (tid < 12) sG[tid] = gamma[tid];
    if (tid < 24) sEoff[tid] = eidx[n*KK + tid] * TAB_STRIDE;
    __syncthreads();

    // ---- scores: 288 (k,a) pairs, strided over 256 threads ----
    for (int j = tid; j < 288; j += 256) {
        int k = j / 12, a = j - k*12;
        const float* krow = tab + sEoff[k];
        // s1: q.k over 48 (12 f4)
        const float4* kq4 = (const float4*)(krow + K1OFF + a*48);
        const float4* qq4 = (const float4*)(sQ1 + a*52);
        float s1 = 0.f;
        #pragma unroll
        for (int i = 0; i < 12; ++i) {
            float4 kv = kq4[i], qv = qq4[i];
            s1 += kv.x*qv.x + kv.y*qv.y + kv.z*qv.z + kv.w*qv.w;
        }
        // bias: x2 . WbiaT over 128 (32 f4)
        const float4* xr4 = (const float4*)(sX2 + k*132);
        const float4* wr4 = (const float4*)(sWbiaT + a*132);
        float bias = 0.f;
        #pragma unroll 8
        for (int i = 0; i < 32; ++i) {
            float4 xv = xr4[i], wv = wr4[i];
            bias += xv.x*wv.x + xv.y*wv.y + xv.z*wv.z + xv.w*wv.w;
        }
        // s2: || Tq2 - T(k2) ||^2 over 4 points
        const float* k2 = krow + K2OFF + a*12;
        float4 k2a = *(const float4*)(k2);
        float4 k2b = *(const float4*)(k2+4);
        float4 k2c = *(const float4*)(k2+8);
        float kx[4] = {k2a.x, k2a.w, k2b.z, k2c.y};
        float ky[4] = {k2a.y, k2b.x, k2b.w, k2c.z};
        float kz[4] = {k2a.z, k2b.y, k2c.x, k2c.w};
        float ss = 0.f;
        #pragma unroll
        for (int p = 0; p < 4; ++p) {
            #pragma unroll
            for (int i = 0; i < 3; ++i) {
                float tk = sR[i*3]*kx[p] + sR[i*3+1]*ky[p] + sR[i*3+2]*kz[p] + sT[i];
                float d = sTq2[a*12 + p*3 + i] - tk;
                ss += d*d;
            }
        }
        sS[j] = WL*(s1*RSQRT48 + bias - C2*sG[a]*ss);
    }
    __syncthreads();
    // ---- softmax over k per head ----
    if (tid < 12) {
        float m = -1e30f;
        for (int k = 0; k < 24; ++k) m = fmaxf(m, sS[k*12 + tid]);
        float s = 0.f;
        for (int k = 0; k < 24; ++k) s += expf(sS[k*12 + tid] - m);
        sMax[tid] = m;
        sInv[tid] = 1.f / s;
    }
    __syncthreads();
    for (int j = tid; j < 288; j += 256) {
        int a = j % 12;
        sS[j] = expf(sS[j] - sMax[a]) * sInv[a];
    }
    __syncthreads();

    float* catRow = cat + (size_t)n * CAT_STRIDE;

    // ---- out1 (144 f4) + oipa (72 f4): 216 float4 items ----
    for (int j = tid; j < 216; j += 256) {
        if (j < 144) {
            int a = j / 12;
            float4 acc = {0.f, 0.f, 0.f, 0.f};
            #pragma unroll 6
            for (int k = 0; k < 24; ++k) {
                float w = sS[k*12 + a];
                float4 v = *(const float4*)&tab[sEoff[k] + V1OFF + j*4];
                acc.x += w*v.x; acc.y += w*v.y; acc.z += w*v.z; acc.w += w*v.w;
            }
            *(float4*)&catRow[j*4] = acc;
        } else {
            int j4 = j - 144;          // [0,72)
            int a = j4 / 6;
            float4 acc = {0.f, 0.f, 0.f, 0.f};
            #pragma unroll 6
            for (int k = 0; k < 24; ++k) {
                float w = sS[k*12 + a];
                float4 v = *(const float4*)&tab[sEoff[k] + V2OFF + j4*4];
                acc.x += w*v.x; acc.y += w*v.y; acc.z += w*v.z; acc.w += w*v.w;
            }
            *(float4*)&sOipa[j4*4] = acc;
        }
    }
    // ---- out2: 384 f4 ----
    for (int j = tid; j < 384; j += 256) {
        int a = j >> 5, i4 = j & 31;
        float4 acc = {0.f, 0.f, 0.f, 0.f};
        #pragma unroll 8
        for (int k = 0; k < 24; ++k) {
            float w = sS[k*12 + a];
            float4 v = *(const float4*)&sX2[k*132 + i4*4];
            acc.x += w*v.x; acc.y += w*v.y; acc.z += w*v.z; acc.w += w*v.w;
        }
        *(float4*)&catRow[CAT_OUT2 + j*4] = acc;
    }
    __syncthreads();
    // ---- inverse transform + norm: 96 points ----
    if (tid < 96) {
        int a = tid / 8, p = tid % 8;
        float o0 = sOipa[a*24 + p*3 + 0] - sT[0];
        float o1 = sOipa[a*24 + p*3 + 1] - sT[1];
        float o2 = sOipa[a*24 + p*3 + 2] - sT[2];
        float m0 = sR[0]*o0 + sR[3]*o1 + sR[6]*o2;
        float m1 = sR[1]*o0 + sR[4]*o1 + sR[7]*o2;
        float m2 = sR[2]*o0 + sR[5]*o1 + sR[8]*o2;
        catRow[CAT_OIPA + a*24 + p*3 + 0] = m0;
        catRow[CAT_OIPA + a*24 + p*3 + 1] = m1;
        catRow[CAT_OIPA + a*24 + p*3 + 2] = m2;
        catRow[CAT_ONRM + a*8 + p] = sqrtf(m0*m0 + m1*m1 + m2*m2);
    }
}

// ----------------------------------- reduce partials + residual + layernorm -
__global__ __launch_bounds__(256) void ln_kernel(
    const float* __restrict__ part, const float* __restrict__ x1,
    const float* __restrict__ bback, const float* __restrict__ g,
    const float* __restrict__ b, float* __restrict__ out)
{
    int n = blockIdx.x;
    int tid = threadIdx.x;
    size_t off = (size_t)n*IFZ + tid;
    float h = 1.4142135623730951f * x1[off] + bback[tid];
    #pragma unroll
    for (int s = 0; s < SPLITK; ++s)
        h += part[(size_t)s*NN*IFZ + off];
    float s = h, s2 = h*h;
    #pragma unroll
    for (int off2 = 32; off2 > 0; off2 >>= 1) {
        s  += __shfl_down(s,  off2);
        s2 += __shfl_down(s2, off2);
    }
    __shared__ float ws[4], ws2[4];
    int w = tid >> 6;
    if ((tid & 63) == 0) { ws[w] = s; ws2[w] = s2; }
    __syncthreads();
    float S  = ws[0] + ws[1] + ws[2] + ws[3];
    float S2 = ws2[0] + ws2[1] + ws2[2] + ws2[3];
    float mu = S * (1.f/IFZ);
    float var = S2 * (1.f/IFZ) - mu*mu;
    out[off] = (h - mu) / sqrtf(var + 1e-5f) * g[tid] + b[tid];
}

// ---------------------------------------------------------------- launch ----
extern "C" void kernel_launch(void* const* d_in, const int* in_sizes, int n_in,
                              void* d_out, int out_size, void* d_ws, size_t ws_size,
                              hipStream_t stream)
{
    const float* x1      = (const float*)d_in[0];
    const float* x2      = (const float*)d_in[1];
    const float* affines = (const float*)d_in[2];
    const float* pos_emb = (const float*)d_in[3];
    const int*   eidx    = (const int*)  d_in[4];
    const float* Wq1     = (const float*)d_in[5];
    const float* Wk1     = (const float*)d_in[6];
    const float* Wv1     = (const float*)d_in[7];
    const float* Wq2     = (const float*)d_in[8];
    const float* Wk2     = (const float*)d_in[9];
    const float* Wv2     = (const float*)d_in[10];
    const float* Wbia    = (const float*)d_in[11];
    const float* gamma   = (const float*)d_in[12];
    const float* Wback   = (const float*)d_in[13];
    const float* bback   = (const float*)d_in[14];
    const float* ln_g    = (const float*)d_in[15];
    const float* ln_b    = (const float*)d_in[16];
    float* out = (float*)d_out;

    float* ws0 = (float*)d_ws;
    float* packW   = ws0;                                   // 256*2304  = 2.36 MB
    float* nodeTab = packW + (size_t)IFZ*TAB_STRIDE;        // 4096*2304 = 37.7 MB
    float* catBuf  = nodeTab + (size_t)NN*TAB_STRIDE;       // 4096*2496 = 40.9 MB
    float* partBuf = nodeTab;  // reuse: nodeTab is dead after attn (6*4.19 MB)

    // 0) pack weights
    pack_w<<<(IFZ*TAB_STRIDE)/256, 256, 0, stream>>>(Wq1, Wk1, Wv1, Wq2, Wk2, Wv2, packW);
    // 1) projections: nodeTab = x1 @ packW
    gemm1<<<dim3(TAB_STRIDE/64, NN/64), 256, 0, stream>>>(x1, packW, nodeTab, NN, TAB_STRIDE, IFZ);
    // 1b) rope + affine transforms in place
    epilogue1<<<NN/4, 256, 0, stream>>>(nodeTab, pos_emb, affines);
    // 2) fused attention -> cat
    attn_kernel<<<NN, 256, 0, stream>>>(nodeTab, x2, affines, Wbia, gamma, eidx, catBuf);
    // 3) back-projection, split-K -> partials (overwrites nodeTab region)
    gemm3s<<<dim3(IFZ/64, NN/64, SPLITK), 256, 0, stream>>>(catBuf, Wback, partBuf);
    // 4) reduce + residual + layernorm -> out
    ln_kernel<<<NN, 256, 0, stream>>>(partBuf, x1, bback, ln_g, ln_b, out);
}

// Round 5
// 386.500 us; speedup vs baseline: 1.3294x; 1.0635x over previous
//
#include <hip/hip_runtime.h>
#include <hip/hip_bf16.h>
#include <math.h>

// Problem constants
#define NN   4096
#define KK   24
#define IFZ  256
#define AH   12
#define AF   48
#define QP   4
#define VP   8

// nodeTab layout (floats per node, stride 2304):
//  [0,576)     q1 (roped in-place)
//  [576,1152)  k1 (roped in-place)
//  [1152,1728) v1
//  [1728,1872) q2 -> Tq2 (transformed in place)
//  [1872,2016) k2 (raw)
//  [2016,2304) v2 -> Tv2 (transformed in place)
#define TAB_STRIDE 2304
#define Q1OFF 0
#define K1OFF 576
#define V1OFF 1152
#define Q2OFF 1728
#define K2OFF 1872
#define V2OFF 2016

#define CAT_STRIDE 2496   // out1 576 | out2 1536 | oipa 288 | onorm 96
#define CAT_OUT2 576
#define CAT_OIPA 2112
#define CAT_ONRM 2400

#define SPLITK 6          // gemm3 split-K chunks: 6 x 416 (13 x 32) = 2496

#define WL      0.57735026918962576f   // sqrt(1/3)
#define C2      0.023570226039551584f  // 0.1*sqrt(2/(9*QP))
#define RSQRT48 0.14433756729740643f

// ---------------------------------------------------------------- pack W ----
__global__ __launch_bounds__(256) void pack_w(
    const float* __restrict__ Wq1, const float* __restrict__ Wk1,
    const float* __restrict__ Wv1, const float* __restrict__ Wq2,
    const float* __restrict__ Wk2, const float* __restrict__ Wv2,
    float* __restrict__ packW)
{
    int idx = blockIdx.x * 256 + threadIdx.x;   // < 256*2304
    int i = idx / TAB_STRIDE;
    int j = idx % TAB_STRIDE;
    float v;
    if (j < 576)       v = Wq1[i*576 + j];
    else if (j < 1152) v = Wk1[i*576 + (j-576)];
    else if (j < 1728) v = Wv1[i*576 + (j-1152)];
    else if (j < 1872) v = Wq2[i*144 + (j-1728)];
    else if (j < 2016) v = Wk2[i*144 + (j-1872)];
    else               v = Wv2[i*288 + (j-2016)];
    packW[idx] = v;
}

// -------------------------------------------------------------- GEMM 1 ------
// C[M x Nc] = A[M x Kc] * B[Kc x Nc], row-major. BM=BN=64, BK=32.
__global__ __launch_bounds__(256) void gemm1(
    const float* __restrict__ A, const float* __restrict__ B,
    float* __restrict__ C, int M, int Nc, int Kc)
{
    __shared__ __align__(16) float sA[32][68];
    __shared__ __align__(16) float sB[32][68];
    int bx = blockIdx.x;   // col tile
    int by = blockIdx.y;   // row tile
    int tid = threadIdx.x;
    int tx = tid & 15, ty = tid >> 4;
    float acc[4][4] = {};
    for (int k0 = 0; k0 < Kc; k0 += 32) {
        #pragma unroll
        for (int l = 0; l < 2; ++l) {
            int idx = tid + l*256;
            int m = idx >> 3, k4 = (idx & 7) * 4;
            float4 av = *(const float4*)&A[(size_t)(by*64 + m)*Kc + k0 + k4];
            sA[k4+0][m] = av.x; sA[k4+1][m] = av.y;
            sA[k4+2][m] = av.z; sA[k4+3][m] = av.w;
        }
        #pragma unroll
        for (int l = 0; l < 2; ++l) {
            int idx = tid + l*256;
            int kk = idx >> 4, j = (idx & 15) * 4;
            *(float4*)&sB[kk][j] = *(const float4*)&B[(size_t)(k0 + kk)*Nc + bx*64 + j];
        }
        __syncthreads();
        #pragma unroll
        for (int kk = 0; kk < 32; ++kk) {
            float4 a4 = *(const float4*)&sA[kk][ty*4];
            float4 b4 = *(const float4*)&sB[kk][tx*4];
            float a[4] = {a4.x, a4.y, a4.z, a4.w};
            float b[4] = {b4.x, b4.y, b4.z, b4.w};
            #pragma unroll
            for (int u = 0; u < 4; ++u)
                #pragma unroll
                for (int v = 0; v < 4; ++v) acc[u][v] += a[u]*b[v];
        }
        __syncthreads();
    }
    #pragma unroll
    for (int u = 0; u < 4; ++u) {
        float4 o = {acc[u][0], acc[u][1], acc[u][2], acc[u][3]};
        *(float4*)&C[(size_t)(by*64 + ty*4+u)*Nc + bx*64 + tx*4] = o;
    }
}

// --------------------------------------- GEMM 3, split-K (writes partials) --
__global__ __launch_bounds__(256) void gemm3s(
    const float* __restrict__ A, const float* __restrict__ B,
    float* __restrict__ P)
{
    __shared__ __align__(16) float sA[32][68];
    __shared__ __align__(16) float sB[32][68];
    int bx = blockIdx.x;
    int by = blockIdx.y;
    int s  = blockIdx.z;
    int tid = threadIdx.x;
    int tx = tid & 15, ty = tid >> 4;
    const int Kc = CAT_STRIDE, Nc = IFZ;
    float* Pp = P + (size_t)s * NN * IFZ;
    float acc[4][4] = {};
    for (int ki = 0; ki < 13; ++ki) {
        int k0 = s*416 + ki*32;
        #pragma unroll
        for (int l = 0; l < 2; ++l) {
            int idx = tid + l*256;
            int m = idx >> 3, k4 = (idx & 7) * 4;
            float4 av = *(const float4*)&A[(size_t)(by*64 + m)*Kc + k0 + k4];
            sA[k4+0][m] = av.x; sA[k4+1][m] = av.y;
            sA[k4+2][m] = av.z; sA[k4+3][m] = av.w;
        }
        #pragma unroll
        for (int l = 0; l < 2; ++l) {
            int idx = tid + l*256;
            int kk = idx >> 4, j = (idx & 15) * 4;
            *(float4*)&sB[kk][j] = *(const float4*)&B[(size_t)(k0 + kk)*Nc + bx*64 + j];
        }
        __syncthreads();
        #pragma unroll
        for (int kk = 0; kk < 32; ++kk) {
            float4 a4 = *(const float4*)&sA[kk][ty*4];
            float4 b4 = *(const float4*)&sB[kk][tx*4];
            float a[4] = {a4.x, a4.y, a4.z, a4.w};
            float b[4] = {b4.x, b4.y, b4.z, b4.w};
            #pragma unroll
            for (int u = 0; u < 4; ++u)
                #pragma unroll
                for (int v = 0; v < 4; ++v) acc[u][v] += a[u]*b[v];
        }
        __syncthreads();
    }
    #pragma unroll
    for (int u = 0; u < 4; ++u) {
        float4 o = {acc[u][0], acc[u][1], acc[u][2], acc[u][3]};
        *(float4*)&Pp[(size_t)(by*64 + ty*4+u)*Nc + bx*64 + tx*4] = o;
    }
}

// ----------------------------------------------------- bias precompute ------
// bias[row][a] = x2row[0:128] . Wbia[:,a], row = n*24+k.  Block = 384 threads
// = 32 rows x 12 heads. WbiaT staged+transposed in LDS once per block.
__global__ __launch_bounds__(384) void bias_kernel(
    const float* __restrict__ x2, const float* __restrict__ Wbia,
    float* __restrict__ biasOut)
{
    __shared__ __align__(16) float sWT[12*132];
    int tid = threadIdx.x;
    {   // 1536 floats = 384 float4, one per thread
        float4 v = *(const float4*)&Wbia[tid*4];
        int base = tid*4;
        float tmp[4] = {v.x, v.y, v.z, v.w};
        #pragma unroll
        for (int c = 0; c < 4; ++c) {
            int fl = base + c;                 // fl = i*12 + a
            int i = fl / 12, a = fl - i*12;
            sWT[a*132 + i] = tmp[c];
        }
    }
    __syncthreads();
    int r_local = tid / 12, a = tid - r_local*12;   // 32 rows, 12 heads
    size_t row = (size_t)blockIdx.x*32 + r_local;
    const float4* xr = (const float4*)&x2[row*128];
    const float4* wr = (const float4*)&sWT[a*132];
    float acc = 0.f;
    #pragma unroll 8
    for (int i = 0; i < 32; ++i) {
        float4 xv = xr[i], wv = wr[i];
        acc += xv.x*wv.x + xv.y*wv.y + xv.z*wv.z + xv.w*wv.w;
    }
    biasOut[row*12 + a] = acc;
}

// --------------------------------------------- per-node rope/affine epilogue
// Trig computed once per node (24 angles) into LDS, not per pair (576x).
__global__ __launch_bounds__(256) void epilogue1(
    float* __restrict__ tab, const float* __restrict__ pos_emb,
    const float* __restrict__ affines)
{
    __shared__ float sC[4][24], sSn[4][24];
    int wv   = threadIdx.x >> 6;
    int node = blockIdx.x * 4 + wv;
    int lane = threadIdx.x & 63;
    float* row = tab + (size_t)node * TAB_STRIDE;

    if (lane < 24) {
        float ang = pos_emb[node*24 + lane];
        sC[wv][lane]  = cosf(ang);
        sSn[wv][lane] = sinf(ang);
    }
    __syncthreads();

    // RoPE q1 (pairs 0..287) and k1 (288..575)
    for (int p = lane; p < 576; p += 64) {
        int part = p / 288;       // 0 -> q1, 1 -> k1
        int pp = p % 288;
        int a = pp / 24, t = pp % 24;
        float c = sC[wv][t], s = sSn[wv][t];
        float* b = row + part*576 + a*48 + 2*t;
        float xe = b[0], xo = b[1];
        b[0] = xe*c - xo*s;
        b[1] = xe*s + xo*c;
    }
    // affine
    float R[9], T[3];
    #pragma unroll
    for (int i = 0; i < 3; ++i) {
        #pragma unroll
        for (int j = 0; j < 3; ++j) R[i*3+j] = affines[node*12 + i*4 + j];
        T[i] = affines[node*12 + i*4 + 3];
    }
    // Tq2 (48 triples) then Tv2 (96 triples)
    for (int q = lane; q < 144; q += 64) {
        float* b = (q < 48) ? (row + Q2OFF + q*3) : (row + V2OFF + (q-48)*3);
        float x = b[0], y = b[1], z = b[2];
        b[0] = R[0]*x + R[1]*y + R[2]*z + T[0];
        b[1] = R[3]*x + R[4]*y + R[5]*z + T[1];
        b[2] = R[6]*x + R[7]*y + R[8]*z + T[2];
    }
}

// ------------------------------------------------------------ attention -----
// One block per node, 256 threads. Bias precomputed; all gathers float4.
__global__ __launch_bounds__(256) void attn_kernel(
    const float* __restrict__ tab, const float* __restrict__ x2,
    const float* __restrict__ affines, const float* __restrict__ biasIn,
    const float* __restrict__ gamma, const int* __restrict__ eidx,
    float* __restrict__ cat)
{
    int n = blockIdx.x;
    int tid = threadIdx.x;

    __shared__ __align__(16) float sQ1[12*52];
    __shared__ __align__(16) float sTq2[144];
    __shared__ __align__(16) float sX2[24*132];
    __shared__ __align__(16) float sBias[288];
    __shared__ float sS[288];
    __shared__ float sOipa[288];
    __shared__ float sR[9], sT[3], sG[12];
    __shared__ int   sEoff[24];
    __shared__ float sMax[12], sInv[12];

    const float* row = tab + (size_t)n * TAB_STRIDE;

    // ---- staging (all float4) ----
    for (int j = tid; j < 144; j += 256) {            // q1: 144 f4
        int a = j / 12, r = j % 12;
        *(float4*)&sQ1[a*52 + r*4] = *(const float4*)&row[Q1OFF + j*4];
    }
    for (int j = tid; j < 36; j += 256)               // Tq2: 36 f4
        *(float4*)&sTq2[j*4] = *(const float4*)&row[Q2OFF + j*4];
    for (int j = tid; j < 768; j += 256) {            // x2: 24 x 32 f4
        int k = j >> 5, i4 = j & 31;
        *(float4*)&sX2[k*132 + i4*4] =
            *(const float4*)&x2[(size_t)n*(KK*128) + k*128 + i4*4];
    }
    for (int j = tid; j < 72; j += 256)               // bias: 72 f4
        *(float4*)&sBias[j*4] = *(const float4*)&biasIn[(size_t)n*288 + j*4];
    if (tid < 9)  sR[tid] = affines[n*12 + (tid/3)*4 + (tid%3)];
    if (tid < 3)  sT[tid] = affines[n*12 + tid*4 + 3];
    if (tid < 12) sG[tid] = gamma[tid];
    if (tid < 24) sEoff[tid] = eidx[n*KK + tid] * TAB_STRIDE;
    __syncthreads();

    // ---- scores: 288 (k,a) pairs, strided over 256 threads ----
    for (int j = tid; j < 288; j += 256) {
        int k = j / 12, a = j - k*12;
        const float* krow = tab + sEoff[k];
        // s1: q.k over 48 (12 f4)
        const float4* kq4 = (const float4*)(krow + K1OFF + a*48);
        const float4* qq4 = (const float4*)(sQ1 + a*52);
        float s1 = 0.f;
        #pragma unroll
        for (int i = 0; i < 12; ++i) {
            float4 kv = kq4[i], qv = qq4[i];
            s1 += kv.x*qv.x + kv.y*qv.y + kv.z*qv.z + kv.w*qv.w;
        }
        // s2: || Tq2 - T(k2) ||^2 over 4 points
        const float* k2 = krow + K2OFF + a*12;
        float4 k2a = *(const float4*)(k2);
        float4 k2b = *(const float4*)(k2+4);
        float4 k2c = *(const float4*)(k2+8);
        float kx[4] = {k2a.x, k2a.w, k2b.z, k2c.y};
        float ky[4] = {k2a.y, k2b.x, k2b.w, k2c.z};
        float kz[4] = {k2a.z, k2b.y, k2c.x, k2c.w};
        float ss = 0.f;
        #pragma unroll
        for (int p = 0; p < 4; ++p) {
            #pragma unroll
            for (int i = 0; i < 3; ++i) {
                float tk = sR[i*3]*kx[p] + sR[i*3+1]*ky[p] + sR[i*3+2]*kz[p] + sT[i];
                float d = sTq2[a*12 + p*3 + i] - tk;
                ss += d*d;
            }
        }
        sS[j] = WL*(s1*RSQRT48 + sBias[j] - C2*sG[a]*ss);
    }
    __syncthreads();
    // ---- softmax over k per head ----
    if (tid < 12) {
        float m = -1e30f;
        for (int k = 0; k < 24; ++k) m = fmaxf(m, sS[k*12 + tid]);
        float s = 0.f;
        for (int k = 0; k < 24; ++k) s += expf(sS[k*12 + tid] - m);
        sMax[tid] = m;
        sInv[tid] = 1.f / s;
    }
    __syncthreads();
    for (int j = tid; j < 288; j += 256) {
        int a = j % 12;
        sS[j] = expf(sS[j] - sMax[a]) * sInv[a];
    }
    __syncthreads();

    float* catRow = cat + (size_t)n * CAT_STRIDE;

    // ---- out1 (144 f4) + oipa (72 f4): 216 float4 items ----
    for (int j = tid; j < 216; j += 256) {
        if (j < 144) {
            int a = j / 12;
            float4 acc = {0.f, 0.f, 0.f, 0.f};
            #pragma unroll 8
            for (int k = 0; k < 24; ++k) {
                float w = sS[k*12 + a];
                float4 v = *(const float4*)&tab[sEoff[k] + V1OFF + j*4];
                acc.x += w*v.x; acc.y += w*v.y; acc.z += w*v.z; acc.w += w*v.w;
            }
            *(float4*)&catRow[j*4] = acc;
        } else {
            int j4 = j - 144;          // [0,72)
            int a = j4 / 6;
            float4 acc = {0.f, 0.f, 0.f, 0.f};
            #pragma unroll 8
            for (int k = 0; k < 24; ++k) {
                float w = sS[k*12 + a];
                float4 v = *(const float4*)&tab[sEoff[k] + V2OFF + j4*4];
                acc.x += w*v.x; acc.y += w*v.y; acc.z += w*v.z; acc.w += w*v.w;
            }
            *(float4*)&sOipa[j4*4] = acc;
        }
    }
    // ---- out2: 384 f4 ----
    for (int j = tid; j < 384; j += 256) {
        int a = j >> 5, i4 = j & 31;
        float4 acc = {0.f, 0.f, 0.f, 0.f};
        #pragma unroll 8
        for (int k = 0; k < 24; ++k) {
            float w = sS[k*12 + a];
            float4 v = *(const float4*)&sX2[k*132 + i4*4];
            acc.x += w*v.x; acc.y += w*v.y; acc.z += w*v.z; acc.w += w*v.w;
        }
        *(float4*)&catRow[CAT_OUT2 + j*4] = acc;
    }
    __syncthreads();
    // ---- inverse transform + norm: 96 points ----
    if (tid < 96) {
        int a = tid / 8, p = tid % 8;
        float o0 = sOipa[a*24 + p*3 + 0] - sT[0];
        float o1 = sOipa[a*24 + p*3 + 1] - sT[1];
        float o2 = sOipa[a*24 + p*3 + 2] - sT[2];
        float m0 = sR[0]*o0 + sR[3]*o1 + sR[6]*o2;
        float m1 = sR[1]*o0 + sR[4]*o1 + sR[7]*o2;
        float m2 = sR[2]*o0 + sR[5]*o1 + sR[8]*o2;
        catRow[CAT_OIPA + a*24 + p*3 + 0] = m0;
        catRow[CAT_OIPA + a*24 + p*3 + 1] = m1;
        catRow[CAT_OIPA + a*24 + p*3 + 2] = m2;
        catRow[CAT_ONRM + a*8 + p] = sqrtf(m0*m0 + m1*m1 + m2*m2);
    }
}

// ----------------------------------- reduce partials + residual + layernorm -
__global__ __launch_bounds__(256) void ln_kernel(
    const float* __restrict__ part, const float* __restrict__ x1,
    const float* __restrict__ bback, const float* __restrict__ g,
    const float* __restrict__ b, float* __restrict__ out)
{
    int n = blockIdx.x;
    int tid = threadIdx.x;
    size_t off = (size_t)n*IFZ + tid;
    float h = 1.4142135623730951f * x1[off] + bback[tid];
    #pragma unroll
    for (int s = 0; s < SPLITK; ++s)
        h += part[(size_t)s*NN*IFZ + off];
    float s = h, s2 = h*h;
    #pragma unroll
    for (int off2 = 32; off2 > 0; off2 >>= 1) {
        s  += __shfl_down(s,  off2);
        s2 += __shfl_down(s2, off2);
    }
    __shared__ float ws[4], ws2[4];
    int w = tid >> 6;
    if ((tid & 63) == 0) { ws[w] = s; ws2[w] = s2; }
    __syncthreads();
    float S  = ws[0] + ws[1] + ws[2] + ws[3];
    float S2 = ws2[0] + ws2[1] + ws2[2] + ws2[3];
    float mu = S * (1.f/IFZ);
    float var = S2 * (1.f/IFZ) - mu*mu;
    out[off] = (h - mu) / sqrtf(var + 1e-5f) * g[tid] + b[tid];
}

// ---------------------------------------------------------------- launch ----
extern "C" void kernel_launch(void* const* d_in, const int* in_sizes, int n_in,
                              void* d_out, int out_size, void* d_ws, size_t ws_size,
                              hipStream_t stream)
{
    const float* x1      = (const float*)d_in[0];
    const float* x2      = (const float*)d_in[1];
    const float* affines = (const float*)d_in[2];
    const float* pos_emb = (const float*)d_in[3];
    const int*   eidx    = (const int*)  d_in[4];
    const float* Wq1     = (const float*)d_in[5];
    const float* Wk1     = (const float*)d_in[6];
    const float* Wv1     = (const float*)d_in[7];
    const float* Wq2     = (const float*)d_in[8];
    const float* Wk2     = (const float*)d_in[9];
    const float* Wv2     = (const float*)d_in[10];
    const float* Wbia    = (const float*)d_in[11];
    const float* gamma   = (const float*)d_in[12];
    const float* Wback   = (const float*)d_in[13];
    const float* bback   = (const float*)d_in[14];
    const float* ln_g    = (const float*)d_in[15];
    const float* ln_b    = (const float*)d_in[16];
    float* out = (float*)d_out;

    float* ws0 = (float*)d_ws;
    float* packW   = ws0;                                   // 256*2304  = 2.36 MB
    float* nodeTab = packW + (size_t)IFZ*TAB_STRIDE;        // 4096*2304 = 37.7 MB
    float* catBuf  = nodeTab + (size_t)NN*TAB_STRIDE;       // 4096*2496 = 40.9 MB
    float* biasBuf = catBuf + (size_t)NN*CAT_STRIDE;        // 4096*288  = 4.7 MB
    float* partBuf = nodeTab;  // reuse: nodeTab dead after attn (6*4.19 MB)

    // 0) pack weights + bias precompute (independent)
    pack_w<<<(IFZ*TAB_STRIDE)/256, 256, 0, stream>>>(Wq1, Wk1, Wv1, Wq2, Wk2, Wv2, packW);
    bias_kernel<<<(NN*KK)/32, 384, 0, stream>>>(x2, Wbia, biasBuf);
    // 1) projections: nodeTab = x1 @ packW
    gemm1<<<dim3(TAB_STRIDE/64, NN/64), 256, 0, stream>>>(x1, packW, nodeTab, NN, TAB_STRIDE, IFZ);
    // 1b) rope + affine transforms in place
    epilogue1<<<NN/4, 256, 0, stream>>>(nodeTab, pos_emb, affines);
    // 2) fused attention -> cat
    attn_kernel<<<NN, 256, 0, stream>>>(nodeTab, x2, affines, biasBuf, gamma, eidx, catBuf);
    // 3) back-projection, split-K -> partials (overwrites nodeTab region)
    gemm3s<<<dim3(IFZ/64, NN/64, SPLITK), 256, 0, stream>>>(catBuf, Wback, partBuf);
    // 4) reduce + residual + layernorm -> out
    ln_kernel<<<NN, 256, 0, stream>>>(partBuf, x1, bback, ln_g, ln_b, out);
}

// Round 8
// 360.728 us; speedup vs baseline: 1.4244x; 1.0714x over previous
//
#include <hip/hip_runtime.h>
#include <hip/hip_bf16.h>
#include <hip/hip_fp16.h>
#include <math.h>

// Problem constants
#define NN   4096
#define KK   24
#define IFZ  256
#define AH   12
#define AF   48
#define QP   4
#define VP   8

// nodeTab layout (floats per node, stride 2304):
//  [0,576)     q1 (roped in-place)        <- live after epilogue
//  [576,1152)  k1 (raw; fp16 copy roped)  <- dead after epilogue
//  [1152,1728) v1 (raw; fp16 copy)        <- dead after epilogue
//  [1728,1872) q2 -> Tq2 (in place)       <- live after epilogue
//  [1872,2016) k2 (raw; fp16 copy)        <- dead after epilogue
//  [2016,2304) v2 (raw; fp16 Tv2 copy)    <- dead after epilogue
#define TAB_STRIDE 2304
#define Q1OFF 0
#define K1OFF 576
#define V1OFF 1152
#define Q2OFF 1728
#define K2OFF 1872
#define V2OFF 2016

// fp16 gather table (halves per node, stride 1648 = 3296 B, all sections 16B-aligned)
#define GT_STRIDE 1648
#define GT_K1 0        // 576 halves: roped k1, [a][48]
#define GT_V1 576      // 576 halves: v1, [a][48]
#define GT_V2 1152     // 288 halves: Tv2, [a][24]
#define GT_K2 1440     // 192 halves: raw k2, [a][16] (12 used + 4 pad)

#define CAT_STRIDE 2496   // out1 576 | out2 1536 | oipa 288 | onorm 96
#define CAT_OUT2 576
#define CAT_OIPA 2112
#define CAT_ONRM 2400

#define SPLITK 6          // gemm3 split-K chunks: 6 x 416 (13 x 32) = 2496

#define WL      0.57735026918962576f   // sqrt(1/3)
#define C2      0.023570226039551584f  // 0.1*sqrt(2/(9*QP))
#define RSQRT48 0.14433756729740643f

// ---------------------------------------------------------------- pack W ----
__global__ __launch_bounds__(256) void pack_w(
    const float* __restrict__ Wq1, const float* __restrict__ Wk1,
    const float* __restrict__ Wv1, const float* __restrict__ Wq2,
    const float* __restrict__ Wk2, const float* __restrict__ Wv2,
    float* __restrict__ packW)
{
    int idx = blockIdx.x * 256 + threadIdx.x;   // < 256*2304
    int i = idx / TAB_STRIDE;
    int j = idx % TAB_STRIDE;
    float v;
    if (j < 576)       v = Wq1[i*576 + j];
    else if (j < 1152) v = Wk1[i*576 + (j-576)];
    else if (j < 1728) v = Wv1[i*576 + (j-1152)];
    else if (j < 1872) v = Wq2[i*144 + (j-1728)];
    else if (j < 2016) v = Wk2[i*144 + (j-1872)];
    else               v = Wv2[i*288 + (j-2016)];
    packW[idx] = v;
}

// -------------------------------------------------------------- GEMM 1 ------
__global__ __launch_bounds__(256) void gemm1(
    const float* __restrict__ A, const float* __restrict__ B,
    float* __restrict__ C, int M, int Nc, int Kc)
{
    __shared__ __align__(16) float sA[32][68];
    __shared__ __align__(16) float sB[32][68];
    int bx = blockIdx.x;   // col tile
    int by = blockIdx.y;   // row tile
    int tid = threadIdx.x;
    int tx = tid & 15, ty = tid >> 4;
    float acc[4][4] = {};
    for (int k0 = 0; k0 < Kc; k0 += 32) {
        #pragma unroll
        for (int l = 0; l < 2; ++l) {
            int idx = tid + l*256;
            int m = idx >> 3, k4 = (idx & 7) * 4;
            float4 av = *(const float4*)&A[(size_t)(by*64 + m)*Kc + k0 + k4];
            sA[k4+0][m] = av.x; sA[k4+1][m] = av.y;
            sA[k4+2][m] = av.z; sA[k4+3][m] = av.w;
        }
        #pragma unroll
        for (int l = 0; l < 2; ++l) {
            int idx = tid + l*256;
            int kk = idx >> 4, j = (idx & 15) * 4;
            *(float4*)&sB[kk][j] = *(const float4*)&B[(size_t)(k0 + kk)*Nc + bx*64 + j];
        }
        __syncthreads();
        #pragma unroll
        for (int kk = 0; kk < 32; ++kk) {
            float4 a4 = *(const float4*)&sA[kk][ty*4];
            float4 b4 = *(const float4*)&sB[kk][tx*4];
            float a[4] = {a4.x, a4.y, a4.z, a4.w};
            float b[4] = {b4.x, b4.y, b4.z, b4.w};
            #pragma unroll
            for (int u = 0; u < 4; ++u)
                #pragma unroll
                for (int v = 0; v < 4; ++v) acc[u][v] += a[u]*b[v];
        }
        __syncthreads();
    }
    #pragma unroll
    for (int u = 0; u < 4; ++u) {
        float4 o = {acc[u][0], acc[u][1], acc[u][2], acc[u][3]};
        *(float4*)&C[(size_t)(by*64 + ty*4+u)*Nc + bx*64 + tx*4] = o;
    }
}

// --------------------------------------- GEMM 3, split-K (writes partials) --
__global__ __launch_bounds__(256) void gemm3s(
    const float* __restrict__ A, const float* __restrict__ B,
    float* __restrict__ P)
{
    __shared__ __align__(16) float sA[32][68];
    __shared__ __align__(16) float sB[32][68];
    int bx = blockIdx.x;
    int by = blockIdx.y;
    int s  = blockIdx.z;
    int tid = threadIdx.x;
    int tx = tid & 15, ty = tid >> 4;
    const int Kc = CAT_STRIDE, Nc = IFZ;
    float* Pp = P + (size_t)s * NN * IFZ;
    float acc[4][4] = {};
    for (int ki = 0; ki < 13; ++ki) {
        int k0 = s*416 + ki*32;
        #pragma unroll
        for (int l = 0; l < 2; ++l) {
            int idx = tid + l*256;
            int m = idx >> 3, k4 = (idx & 7) * 4;
            float4 av = *(const float4*)&A[(size_t)(by*64 + m)*Kc + k0 + k4];
            sA[k4+0][m] = av.x; sA[k4+1][m] = av.y;
            sA[k4+2][m] = av.z; sA[k4+3][m] = av.w;
        }
        #pragma unroll
        for (int l = 0; l < 2; ++l) {
            int idx = tid + l*256;
            int kk = idx >> 4, j = (idx & 15) * 4;
            *(float4*)&sB[kk][j] = *(const float4*)&B[(size_t)(k0 + kk)*Nc + bx*64 + j];
        }
        __syncthreads();
        #pragma unroll
        for (int kk = 0; kk < 32; ++kk) {
            float4 a4 = *(const float4*)&sA[kk][ty*4];
            float4 b4 = *(const float4*)&sB[kk][tx*4];
            float a[4] = {a4.x, a4.y, a4.z, a4.w};
            float b[4] = {b4.x, b4.y, b4.z, b4.w};
            #pragma unroll
            for (int u = 0; u < 4; ++u)
                #pragma unroll
                for (int v = 0; v < 4; ++v) acc[u][v] += a[u]*b[v];
        }
        __syncthreads();
    }
    #pragma unroll
    for (int u = 0; u < 4; ++u) {
        float4 o = {acc[u][0], acc[u][1], acc[u][2], acc[u][3]};
        *(float4*)&Pp[(size_t)(by*64 + ty*4+u)*Nc + bx*64 + tx*4] = o;
    }
}

// ----------------------------------------------------- bias precompute ------
__global__ __launch_bounds__(384) void bias_kernel(
    const float* __restrict__ x2, const float* __restrict__ Wbia,
    float* __restrict__ biasOut)
{
    __shared__ __align__(16) float sWT[12*132];
    int tid = threadIdx.x;
    {   // 1536 floats = 384 float4, one per thread
        float4 v = *(const float4*)&Wbia[tid*4];
        int base = tid*4;
        float tmp[4] = {v.x, v.y, v.z, v.w};
        #pragma unroll
        for (int c = 0; c < 4; ++c) {
            int fl = base + c;                 // fl = i*12 + a
            int i = fl / 12, a = fl - i*12;
            sWT[a*132 + i] = tmp[c];
        }
    }
    __syncthreads();
    int r_local = tid / 12, a = tid - r_local*12;   // 32 rows, 12 heads
    size_t row = (size_t)blockIdx.x*32 + r_local;
    const float4* xr = (const float4*)&x2[row*128];
    const float4* wr = (const float4*)&sWT[a*132];
    float acc = 0.f;
    #pragma unroll 8
    for (int i = 0; i < 32; ++i) {
        float4 xv = xr[i], wv = wr[i];
        acc += xv.x*wv.x + xv.y*wv.y + xv.z*wv.z + xv.w*wv.w;
    }
    biasOut[row*12 + a] = acc;
}

// --------------------- per-node rope/affine epilogue + fp16 gather table ----
// Per node: rope q1 (in place, fp32), rope k1 -> fp16, v1 -> fp16,
// Tq2 (in place, fp32), Tv2 -> fp16, raw k2 -> fp16.
__global__ __launch_bounds__(256) void epilogue1(
    float* __restrict__ tab, __half* __restrict__ gtab,
    const float* __restrict__ pos_emb, const float* __restrict__ affines)
{
    __shared__ float sC[4][24], sSn[4][24];
    int wv   = threadIdx.x >> 6;
    int node = blockIdx.x * 4 + wv;
    int lane = threadIdx.x & 63;
    float* row = tab + (size_t)node * TAB_STRIDE;
    __half* grow = gtab + (size_t)node * GT_STRIDE;

    if (lane < 24) {
        float ang = pos_emb[node*24 + lane];
        sC[wv][lane]  = cosf(ang);
        sSn[wv][lane] = sinf(ang);
    }
    __syncthreads();

    // q1: rope in place (288 pairs)
    for (int p = lane; p < 288; p += 64) {
        int a = p / 24, t = p % 24;
        float c = sC[wv][t], s = sSn[wv][t];
        float* b = row + Q1OFF + a*48 + 2*t;
        float xe = b[0], xo = b[1];
        b[0] = xe*c - xo*s;
        b[1] = xe*s + xo*c;
    }
    // k1: rope -> fp16 table (288 pairs)
    for (int p = lane; p < 288; p += 64) {
        int a = p / 24, t = p % 24;
        float c = sC[wv][t], s = sSn[wv][t];
        const float* b = row + K1OFF + a*48 + 2*t;
        float xe = b[0], xo = b[1];
        *(__half2*)&grow[GT_K1 + a*48 + 2*t] =
            __floats2half2_rn(xe*c - xo*s, xe*s + xo*c);
    }
    // v1 -> fp16 (288 half2)
    for (int i = lane; i < 288; i += 64) {
        float2 v = *(const float2*)&row[V1OFF + i*2];
        *(__half2*)&grow[GT_V1 + i*2] = __floats2half2_rn(v.x, v.y);
    }
    // affine
    float R[9], T[3];
    #pragma unroll
    for (int i = 0; i < 3; ++i) {
        #pragma unroll
        for (int j = 0; j < 3; ++j) R[i*3+j] = affines[node*12 + i*4 + j];
        T[i] = affines[node*12 + i*4 + 3];
    }
    // Tq2 in place (48 triples)
    for (int q = lane; q < 48; q += 64) {
        float* b = row + Q2OFF + q*3;
        float x = b[0], y = b[1], z = b[2];
        b[0] = R[0]*x + R[1]*y + R[2]*z + T[0];
        b[1] = R[3]*x + R[4]*y + R[5]*z + T[1];
        b[2] = R[6]*x + R[7]*y + R[8]*z + T[2];
    }
    // Tv2 -> fp16 (96 triples)
    for (int q = lane; q < 96; q += 64) {
        const float* b = row + V2OFF + q*3;
        float x = b[0], y = b[1], z = b[2];
        grow[GT_V2 + q*3 + 0] = (__half)(R[0]*x + R[1]*y + R[2]*z + T[0]);
        grow[GT_V2 + q*3 + 1] = (__half)(R[3]*x + R[4]*y + R[5]*z + T[1]);
        grow[GT_V2 + q*3 + 2] = (__half)(R[6]*x + R[7]*y + R[8]*z + T[2]);
    }
    // k2 raw -> fp16 ([a][16] padded rows; 72 half2)
    for (int i = lane; i < 72; i += 64) {
        int a = i / 6, w = i % 6;
        float2 v = *(const float2*)&row[K2OFF + a*12 + w*2];
        *(__half2*)&grow[GT_K2 + a*16 + w*2] = __floats2half2_rn(v.x, v.y);
    }
}

// ------------------------------------------------------------ attention -----
// One block per node, 256 threads. Gathers read the compact fp16 table.
__global__ __launch_bounds__(256) void attn_kernel(
    const float* __restrict__ tab, const __half* __restrict__ gtab,
    const float* __restrict__ x2, const float* __restrict__ affines,
    const float* __restrict__ biasIn, const float* __restrict__ gamma,
    const int* __restrict__ eidx, float* __restrict__ cat)
{
    int n = blockIdx.x;
    int tid = threadIdx.x;

    __shared__ __align__(16) float  sQ1[12*52];
    __shared__ __align__(16) float  sTq2[144];
    __shared__ __align__(16) __half sX2h[24*136];
    __shared__ __align__(16) float  sBias[288];
    __shared__ float sS[288];
    __shared__ float sOipa[288];
    __shared__ float sR[9], sT[3], sG[12];
    __shared__ int   sEoff[24];
    __shared__ float sMax[12], sInv[12];

    const float* row = tab + (size_t)n * TAB_STRIDE;

    // ---- staging ----
    for (int j = tid; j < 144; j += 256) {            // q1: 144 f4 (fp32)
        int a = j / 12, r = j % 12;
        *(float4*)&sQ1[a*52 + r*4] = *(const float4*)&row[Q1OFF + j*4];
    }
    for (int j = tid; j < 36; j += 256)               // Tq2: 36 f4 (fp32)
        *(float4*)&sTq2[j*4] = *(const float4*)&row[Q2OFF + j*4];
    for (int j = tid; j < 768; j += 256) {            // x2 -> fp16 LDS
        int k = j >> 5, i4 = j & 31;
        float4 v = *(const float4*)&x2[(size_t)n*(KK*128) + k*128 + i4*4];
        __half2* dst = (__half2*)(sX2h + k*136 + i4*4);
        dst[0] = __floats2half2_rn(v.x, v.y);
        dst[1] = __floats2half2_rn(v.z, v.w);
    }
    for (int j = tid; j < 72; j += 256)               // bias: 72 f4
        *(float4*)&sBias[j*4] = *(const float4*)&biasIn[(size_t)n*288 + j*4];
    if (tid < 9)  sR[tid] = affines[n*12 + (tid/3)*4 + (tid%3)];
    if (tid < 3)  sT[tid] = affines[n*12 + tid*4 + 3];
    if (tid < 12) sG[tid] = gamma[tid];
    if (tid < 24) sEoff[tid] = eidx[n*KK + tid] * GT_STRIDE;
    __syncthreads();

    // ---- scores: 288 (k,a) pairs ----
    for (int j = tid; j < 288; j += 256) {
        int k = j / 12, a = j - k*12;
        const __half* krow = gtab + sEoff[k];
        // s1: q.k over 48
        const __half2* kq2 = (const __half2*)(krow + GT_K1 + a*48);
        const float4*  qq4 = (const float4*)(sQ1 + a*52);
        float s1 = 0.f;
        #pragma unroll
        for (int i = 0; i < 12; ++i) {
            float4 qv = qq4[i];
            float2 f0 = __half22float2(kq2[2*i]);
            float2 f1 = __half22float2(kq2[2*i+1]);
            s1 += qv.x*f0.x + qv.y*f0.y + qv.z*f1.x + qv.w*f1.y;
        }
        // s2: || Tq2 - T(k2) ||^2 over 4 points
        const __half2* k22 = (const __half2*)(krow + GT_K2 + a*16);
        float k2f[12];
        #pragma unroll
        for (int i = 0; i < 6; ++i) {
            float2 f = __half22float2(k22[i]);
            k2f[2*i] = f.x; k2f[2*i+1] = f.y;
        }
        float ss = 0.f;
        #pragma unroll
        for (int p = 0; p < 4; ++p) {
            float kx = k2f[p*3], ky = k2f[p*3+1], kz = k2f[p*3+2];
            #pragma unroll
            for (int i = 0; i < 3; ++i) {
                float tk = sR[i*3]*kx + sR[i*3+1]*ky + sR[i*3+2]*kz + sT[i];
                float d = sTq2[a*12 + p*3 + i] - tk;
                ss += d*d;
            }
        }
        sS[j] = WL*(s1*RSQRT48 + sBias[j] - C2*sG[a]*ss);
    }
    __syncthreads();
    // ---- softmax over k per head ----
    if (tid < 12) {
        float m = -1e30f;
        for (int k = 0; k < 24; ++k) m = fmaxf(m, sS[k*12 + tid]);
        float s = 0.f;
        for (int k = 0; k < 24; ++k) s += expf(sS[k*12 + tid] - m);
        sMax[tid] = m;
        sInv[tid] = 1.f / s;
    }
    __syncthreads();
    for (int j = tid; j < 288; j += 256) {
        int a = j % 12;
        sS[j] = expf(sS[j] - sMax[a]) * sInv[a];
    }
    __syncthreads();

    float* catRow = cat + (size_t)n * CAT_STRIDE;

    // ---- out1 (144 x 4 floats) + oipa (72 x 4): fp16 gathers ----
    for (int j = tid; j < 216; j += 256) {
        if (j < 144) {
            int a = j / 12;
            float4 acc = {0.f, 0.f, 0.f, 0.f};
            #pragma unroll 8
            for (int k = 0; k < 24; ++k) {
                float w = sS[k*12 + a];
                const __half2* vp = (const __half2*)(gtab + sEoff[k] + GT_V1 + j*4);
                float2 f0 = __half22float2(vp[0]);
                float2 f1 = __half22float2(vp[1]);
                acc.x += w*f0.x; acc.y += w*f0.y; acc.z += w*f1.x; acc.w += w*f1.y;
            }
            *(float4*)&catRow[j*4] = acc;
        } else {
            int j4 = j - 144;          // [0,72)
            int a = j4 / 6;
            float4 acc = {0.f, 0.f, 0.f, 0.f};
            #pragma unroll 8
            for (int k = 0; k < 24; ++k) {
                float w = sS[k*12 + a];
                const __half2* vp = (const __half2*)(gtab + sEoff[k] + GT_V2 + j4*4);
                float2 f0 = __half22float2(vp[0]);
                float2 f1 = __half22float2(vp[1]);
                acc.x += w*f0.x; acc.y += w*f0.y; acc.z += w*f1.x; acc.w += w*f1.y;
            }
            *(float4*)&sOipa[j4*4] = acc;
        }
    }
    // ---- out2: 384 x 4 floats from fp16 LDS ----
    for (int j = tid; j < 384; j += 256) {
        int a = j >> 5, i4 = j & 31;
        float4 acc = {0.f, 0.f, 0.f, 0.f};
        #pragma unroll 8
        for (int k = 0; k < 24; ++k) {
            float w = sS[k*12 + a];
            const __half2* xp = (const __half2*)(sX2h + k*136 + i4*4);
            float2 f0 = __half22float2(xp[0]);
            float2 f1 = __half22float2(xp[1]);
            acc.x += w*f0.x; acc.y += w*f0.y; acc.z += w*f1.x; acc.w += w*f1.y;
        }
        *(float4*)&catRow[CAT_OUT2 + j*4] = acc;
    }
    __syncthreads();
    // ---- inverse transform + norm: 96 points ----
    if (tid < 96) {
        int a = tid / 8, p = tid % 8;
        float o0 = sOipa[a*24 + p*3 + 0] - sT[0];
        float o1 = sOipa[a*24 + p*3 + 1] - sT[1];
        float o2 = sOipa[a*24 + p*3 + 2] - sT[2];
        float m0 = sR[0]*o0 + sR[3]*o1 + sR[6]*o2;
        float m1 = sR[1]*o0 + sR[4]*o1 + sR[7]*o2;
        float m2 = sR[2]*o0 + sR[5]*o1 + sR[8]*o2;
        catRow[CAT_OIPA + a*24 + p*3 + 0] = m0;
        catRow[CAT_OIPA + a*24 + p*3 + 1] = m1;
        catRow[CAT_OIPA + a*24 + p*3 + 2] = m2;
        catRow[CAT_ONRM + a*8 + p] = sqrtf(m0*m0 + m1*m1 + m2*m2);
    }
}

// ----------------------------------- reduce partials + residual + layernorm -
__global__ __launch_bounds__(256) void ln_kernel(
    const float* __restrict__ part, const float* __restrict__ x1,
    const float* __restrict__ bback, const float* __restrict__ g,
    const float* __restrict__ b, float* __restrict__ out)
{
    int n = blockIdx.x;
    int tid = threadIdx.x;
    size_t off = (size_t)n*IFZ + tid;
    float h = 1.4142135623730951f * x1[off] + bback[tid];
    #pragma unroll
    for (int s = 0; s < SPLITK; ++s)
        h += part[(size_t)s*NN*IFZ + off];
    float s = h, s2 = h*h;
    #pragma unroll
    for (int off2 = 32; off2 > 0; off2 >>= 1) {
        s  += __shfl_down(s,  off2);
        s2 += __shfl_down(s2, off2);
    }
    __shared__ float ws[4], ws2[4];
    int w = tid >> 6;
    if ((tid & 63) == 0) { ws[w] = s; ws2[w] = s2; }
    __syncthreads();
    float S  = ws[0] + ws[1] + ws[2] + ws[3];
    float S2 = ws2[0] + ws2[1] + ws2[2] + ws2[3];
    float mu = S * (1.f/IFZ);
    float var = S2 * (1.f/IFZ) - mu*mu;
    out[off] = (h - mu) / sqrtf(var + 1e-5f) * g[tid] + b[tid];
}

// ---------------------------------------------------------------- launch ----
extern "C" void kernel_launch(void* const* d_in, const int* in_sizes, int n_in,
                              void* d_out, int out_size, void* d_ws, size_t ws_size,
                              hipStream_t stream)
{
    const float* x1      = (const float*)d_in[0];
    const float* x2      = (const float*)d_in[1];
    const float* affines = (const float*)d_in[2];
    const float* pos_emb = (const float*)d_in[3];
    const int*   eidx    = (const int*)  d_in[4];
    const float* Wq1     = (const float*)d_in[5];
    const float* Wk1     = (const float*)d_in[6];
    const float* Wv1     = (const float*)d_in[7];
    const float* Wq2     = (const float*)d_in[8];
    const float* Wk2     = (const float*)d_in[9];
    const float* Wv2     = (const float*)d_in[10];
    const float* Wbia    = (const float*)d_in[11];
    const float* gamma   = (const float*)d_in[12];
    const float* Wback   = (const float*)d_in[13];
    const float* bback   = (const float*)d_in[14];
    const float* ln_g    = (const float*)d_in[15];
    const float* ln_b    = (const float*)d_in[16];
    float* out = (float*)d_out;

    float* ws0 = (float*)d_ws;
    float*  packW   = ws0;                                   // 256*2304  = 2.36 MB
    float*  nodeTab = packW + (size_t)IFZ*TAB_STRIDE;        // 4096*2304 = 37.7 MB
    float*  catBuf  = nodeTab + (size_t)NN*TAB_STRIDE;       // 4096*2496 = 40.9 MB
    float*  biasBuf = catBuf + (size_t)NN*CAT_STRIDE;        // 4096*288  = 4.7 MB
    __half* gatherTab = (__half*)(biasBuf + (size_t)NN*288); // 4096*1648*2B = 13.5 MB
    float*  partBuf = nodeTab;  // reuse: nodeTab dead after attn (6*4.19 MB)

    // 0) pack weights + bias precompute (independent)
    pack_w<<<(IFZ*TAB_STRIDE)/256, 256, 0, stream>>>(Wq1, Wk1, Wv1, Wq2, Wk2, Wv2, packW);
    bias_kernel<<<(NN*KK)/32, 384, 0, stream>>>(x2, Wbia, biasBuf);
    // 1) projections: nodeTab = x1 @ packW
    gemm1<<<dim3(TAB_STRIDE/64, NN/64), 256, 0, stream>>>(x1, packW, nodeTab, NN, TAB_STRIDE, IFZ);
    // 1b) rope + affine transforms + fp16 gather table
    epilogue1<<<NN/4, 256, 0, stream>>>(nodeTab, gatherTab, pos_emb, affines);
    // 2) fused attention -> cat
    attn_kernel<<<NN, 256, 0, stream>>>(nodeTab, gatherTab, x2, affines, biasBuf, gamma, eidx, catBuf);
    // 3) back-projection, split-K -> partials (overwrites nodeTab region)
    gemm3s<<<dim3(IFZ/64, NN/64, SPLITK), 256, 0, stream>>>(catBuf, Wback, partBuf);
    // 4) reduce + residual + layernorm -> out
    ln_kernel<<<NN, 256, 0, stream>>>(partBuf, x1, bback, ln_g, ln_b, out);
}